// Round 1
// baseline (818.897 us; speedup 1.0000x reference)
//
#include <hip/hip_runtime.h>
#include <hip/hip_bf16.h>

#define DD 64

// ---------------------------------------------------------------------------
// Kernel 1: edge -> node scatter sum + counts.
// 16 threads per edge, each handling a float4 (4 dims). Coalesced loads of
// edge_attr; atomics into node_sum (12.8MB, L2-resident, avg 16 hits/addr).
// ---------------------------------------------------------------------------
__global__ __launch_bounds__(256) void k_scatter(const float* __restrict__ edge_attr,
                                                 const int* __restrict__ eidx,
                                                 float* __restrict__ node_sum,
                                                 float* __restrict__ node_cnt,
                                                 int E) {
  int stride = gridDim.x * blockDim.x;
  int gid = blockIdx.x * blockDim.x + threadIdx.x;
  int total = E * 16;  // 16 float4 chunks per edge (64 dims)
  for (int i = gid; i < total; i += stride) {
    int e = i >> 4;
    int q = i & 15;
    int n = eidx[e];
    const float4 v = *reinterpret_cast<const float4*>(edge_attr + (size_t)e * DD + q * 4);
    float* dst = node_sum + (size_t)n * DD + q * 4;
    atomicAdd(dst + 0, v.x);
    atomicAdd(dst + 1, v.y);
    atomicAdd(dst + 2, v.z);
    atomicAdd(dst + 3, v.w);
  }
  for (int e = gid; e < E; e += stride) {
    atomicAdd(&node_cnt[eidx[e]], 1.0f);
  }
}

// ---------------------------------------------------------------------------
// Kernel 2: node -> graph pooling. One block per graph b. batch is sorted, so
// binary-search the [lo,hi) node range. Computes:
//   u_e[b] = mean_n( node_sum[n]/max(cnt[n],1) ),  u_v[b] = mean_n( x[n] )
// and writes comb[b] = [u_e | u_v | u].
// ---------------------------------------------------------------------------
__global__ __launch_bounds__(256) void k_pool(const float* __restrict__ node_sum,
                                              const float* __restrict__ node_cnt,
                                              const float* __restrict__ x,
                                              const float* __restrict__ u,
                                              const int* __restrict__ batch,
                                              float* __restrict__ comb, int N) {
  __shared__ int s_lo, s_hi;
  __shared__ float rE[4][64], rV[4][64];
  int b = blockIdx.x;
  int tid = threadIdx.x;
  if (tid == 0) {
    int lo = 0, hi = N;
    while (lo < hi) { int m = (lo + hi) >> 1; if (batch[m] < b) lo = m + 1; else hi = m; }
    s_lo = lo;
    hi = N;
    while (lo < hi) { int m = (lo + hi) >> 1; if (batch[m] < b + 1) lo = m + 1; else hi = m; }
    s_hi = lo;
  }
  __syncthreads();
  int lo = s_lo, hi = s_hi;
  int d = tid & 63, sub = tid >> 6;
  float accE = 0.f, accV = 0.f;
  for (int n = lo + sub; n < hi; n += 4) {
    float c = node_cnt[n];
    float inv = 1.0f / fmaxf(c, 1.0f);
    accE += node_sum[(size_t)n * DD + d] * inv;
    accV += x[(size_t)n * DD + d];
  }
  rE[sub][d] = accE;
  rV[sub][d] = accV;
  __syncthreads();
  if (sub == 0) {
    float cnt = fmaxf((float)(hi - lo), 1.0f);
    float ue = (rE[0][d] + rE[1][d] + rE[2][d] + rE[3][d]) / cnt;
    float uv = (rV[0][d] + rV[1][d] + rV[2][d] + rV[3][d]) / cnt;
    float* row = comb + (size_t)b * 192;
    row[d] = ue;
    row[64 + d] = uv;
    row[128 + d] = u[(size_t)b * 64 + d];
  }
}

// ---------------------------------------------------------------------------
// Kernel 3: fused 3-layer MLP + BatchNorm (batch stats), single block of 1024
// threads (thread = (row r=tid>>2, 16-col block cb=tid&3)). B=256 rows, D=64.
// W^T staged in LDS (float4 reads, broadcast across the 4 threads of a row).
// hbuf padded to 65 to keep column reads conflict-free.
// ---------------------------------------------------------------------------
template <int K, bool FIRST, bool LAST>
__device__ __forceinline__ void layer(int tid, const float* __restrict__ gin,
                                      float* wT, float* hbuf, float* ps, float* pq,
                                      float* abuf, float* bbuf,
                                      const float* __restrict__ W,
                                      const float* __restrict__ bias,
                                      const float* __restrict__ gamma,
                                      const float* __restrict__ beta,
                                      float* __restrict__ out) {
  int r = tid >> 2, cb = tid & 3, c0 = cb * 16;
  // stage W transposed: wT[k*64+j] = W[j*K+k]
  for (int i = tid; i < K * 64; i += 1024) {
    int k = i >> 6;
    int j = i & 63;
    wT[i] = W[j * K + k];
  }
  __syncthreads();

  float acc[16];
#pragma unroll
  for (int jj = 0; jj < 16; ++jj) acc[jj] = bias[c0 + jj];

  for (int k = 0; k < K; ++k) {
    float c = FIRST ? gin[(size_t)r * 192 + k] : hbuf[r * 65 + k];
    const float4* wp = reinterpret_cast<const float4*>(&wT[k * 64 + c0]);
#pragma unroll
    for (int jv = 0; jv < 4; ++jv) {
      float4 w = wp[jv];
      acc[jv * 4 + 0] += c * w.x;
      acc[jv * 4 + 1] += c * w.y;
      acc[jv * 4 + 2] += c * w.z;
      acc[jv * 4 + 3] += c * w.w;
    }
  }
#pragma unroll
  for (int jj = 0; jj < 16; ++jj) acc[jj] = fmaxf(acc[jj], 0.f);

  // all threads must finish reading hbuf (layer input) before overwrite
  __syncthreads();
#pragma unroll
  for (int jj = 0; jj < 16; ++jj) hbuf[r * 65 + c0 + jj] = acc[jj];
  __syncthreads();

  // column stats: 16 segments of 16 rows each
  {
    int col = tid & 63, seg = tid >> 6;
    float s = 0.f, sq = 0.f;
#pragma unroll
    for (int t = 0; t < 16; ++t) {
      float v = hbuf[(seg * 16 + t) * 65 + col];
      s += v;
      sq += v * v;
    }
    ps[seg * 64 + col] = s;
    pq[seg * 64 + col] = sq;
  }
  __syncthreads();
  if (tid < 64) {
    float s = 0.f, sq = 0.f;
#pragma unroll
    for (int g = 0; g < 16; ++g) {
      s += ps[g * 64 + tid];
      sq += pq[g * 64 + tid];
    }
    float mu = s * (1.0f / 256.0f);
    float var = sq * (1.0f / 256.0f) - mu * mu;
    float rs = rsqrtf(var + 1e-5f);
    float ga = gamma[tid] * rs;
    abuf[tid] = ga;
    bbuf[tid] = beta[tid] - mu * ga;
  }
  __syncthreads();
#pragma unroll
  for (int jj = 0; jj < 16; ++jj) {
    float v = acc[jj] * abuf[c0 + jj] + bbuf[c0 + jj];
    if (LAST)
      out[(size_t)r * 64 + c0 + jj] = v;
    else
      hbuf[r * 65 + c0 + jj] = v;
  }
  if (!LAST) __syncthreads();
}

__global__ __launch_bounds__(1024) void k_mlp(const float* __restrict__ comb,
                                              const float* W0, const float* b0,
                                              const float* W1, const float* b1,
                                              const float* W2, const float* b2,
                                              const float* g0, const float* be0,
                                              const float* g1, const float* be1,
                                              const float* g2, const float* be2,
                                              float* __restrict__ out) {
  __shared__ float wT[192 * 64];
  __shared__ float hbuf[256 * 65];
  __shared__ float ps[16 * 64], pq[16 * 64];
  __shared__ float abuf[64], bbuf[64];
  int tid = threadIdx.x;
  layer<192, true, false>(tid, comb, wT, hbuf, ps, pq, abuf, bbuf, W0, b0, g0, be0, nullptr);
  layer<64, false, false>(tid, comb, wT, hbuf, ps, pq, abuf, bbuf, W1, b1, g1, be1, nullptr);
  layer<64, false, true>(tid, comb, wT, hbuf, ps, pq, abuf, bbuf, W2, b2, g2, be2, out);
}

extern "C" void kernel_launch(void* const* d_in, const int* in_sizes, int n_in,
                              void* d_out, int out_size, void* d_ws, size_t ws_size,
                              hipStream_t stream) {
  (void)n_in; (void)out_size; (void)ws_size;
  const float* x         = (const float*)d_in[0];
  const float* edge_attr = (const float*)d_in[1];
  const float* u         = (const float*)d_in[2];
  const int*   eidx      = (const int*)d_in[3];  // row 0 = first E entries
  const int*   batch     = (const int*)d_in[4];
  const float* W0 = (const float*)d_in[5];
  const float* b0 = (const float*)d_in[6];
  const float* W1 = (const float*)d_in[7];
  const float* b1 = (const float*)d_in[8];
  const float* W2 = (const float*)d_in[9];
  const float* b2 = (const float*)d_in[10];
  const float* g0 = (const float*)d_in[11];
  const float* be0 = (const float*)d_in[12];
  const float* g1 = (const float*)d_in[13];
  const float* be1 = (const float*)d_in[14];
  const float* g2 = (const float*)d_in[15];
  const float* be2 = (const float*)d_in[16];

  int N = in_sizes[0] / DD;
  int E = in_sizes[1] / DD;
  int B = in_sizes[2] / DD;

  float* node_sum = (float*)d_ws;
  float* node_cnt = node_sum + (size_t)N * DD;
  float* comb = node_cnt + N;

  hipMemsetAsync(node_sum, 0, (size_t)(N * DD + N) * sizeof(float), stream);
  k_scatter<<<4096, 256, 0, stream>>>(edge_attr, eidx, node_sum, node_cnt, E);
  k_pool<<<B, 256, 0, stream>>>(node_sum, node_cnt, x, u, batch, comb, N);
  k_mlp<<<1, 1024, 0, stream>>>(comb, W0, b0, W1, b1, W2, b2,
                                g0, be0, g1, be1, g2, be2, (float*)d_out);
}

// Round 2
// 332.707 us; speedup vs baseline: 2.4613x; 2.4613x over previous
//
#include <hip/hip_runtime.h>
#include <hip/hip_bf16.h>

#define DD 64

// ===========================================================================
// CSR-build path: histogram -> scan -> id-scatter -> gather (no f32 atomics).
// ===========================================================================

__global__ __launch_bounds__(256) void k_hist(const int* __restrict__ eidx,
                                              int* __restrict__ cnt, int E) {
  int gid = blockIdx.x * blockDim.x + threadIdx.x;
  int stride = gridDim.x * blockDim.x;
  for (int e = gid; e < E; e += stride) atomicAdd(&cnt[eidx[e]], 1);
}

// Single-block exclusive scan of cnt[N] -> offs[N+1]; cursor[i] = offs[i].
__global__ __launch_bounds__(1024) void k_scan(const int* __restrict__ cnt,
                                               int* __restrict__ offs,
                                               int* __restrict__ cursor, int N) {
  __shared__ int part[1024];
  int t = threadIdx.x;
  int C = (N + 1023) >> 10;
  int lo = t * C, hi = min(lo + C, N);
  int s = 0;
  for (int i = lo; i < hi; ++i) s += cnt[i];
  part[t] = s;
  __syncthreads();
  for (int off = 1; off < 1024; off <<= 1) {  // Hillis-Steele inclusive scan
    int v = (t >= off) ? part[t - off] : 0;
    __syncthreads();
    part[t] += v;
    __syncthreads();
  }
  int base = part[t] - s;  // exclusive prefix
  for (int i = lo; i < hi; ++i) {
    offs[i] = base;
    cursor[i] = base;
    base += cnt[i];
  }
  if (t == 1023) offs[N] = base;  // lo>=N for last thread => base == total
}

__global__ __launch_bounds__(256) void k_fill(const int* __restrict__ eidx,
                                              int* __restrict__ cursor,
                                              int* __restrict__ eids, int E) {
  int gid = blockIdx.x * blockDim.x + threadIdx.x;
  int stride = gridDim.x * blockDim.x;
  for (int e = gid; e < E; e += stride) {
    int n = eidx[e];
    int slot = atomicAdd(&cursor[n], 1);
    eids[slot] = e;
  }
}

// 16 lanes per node: sum this node's edge rows (coalesced 256B per edge),
// divide by count, write node mean. No atomics.
__global__ __launch_bounds__(256) void k_gather(const float* __restrict__ edge_attr,
                                                const int* __restrict__ eids,
                                                const int* __restrict__ offs,
                                                float* __restrict__ node_mean, int N) {
  int g = blockIdx.x * 16 + (threadIdx.x >> 4);
  int lane = threadIdx.x & 15;
  if (g >= N) return;
  int lo = offs[g], hi = offs[g + 1];
  float4 acc = make_float4(0.f, 0.f, 0.f, 0.f);
  for (int j = lo; j < hi; ++j) {
    int e = eids[j];
    const float4 v = *reinterpret_cast<const float4*>(edge_attr + (size_t)e * DD + lane * 4);
    acc.x += v.x; acc.y += v.y; acc.z += v.z; acc.w += v.w;
  }
  float inv = 1.0f / fmaxf((float)(hi - lo), 1.0f);
  acc.x *= inv; acc.y *= inv; acc.z *= inv; acc.w *= inv;
  *reinterpret_cast<float4*>(node_mean + (size_t)g * DD + lane * 4) = acc;
}

// ===========================================================================
// Fallback (proven round-1) atomic scatter, used only if ws too small.
// ===========================================================================
__global__ __launch_bounds__(256) void k_scatter(const float* __restrict__ edge_attr,
                                                 const int* __restrict__ eidx,
                                                 float* __restrict__ node_sum,
                                                 float* __restrict__ node_cnt,
                                                 int E) {
  int stride = gridDim.x * blockDim.x;
  int gid = blockIdx.x * blockDim.x + threadIdx.x;
  int total = E * 16;
  for (int i = gid; i < total; i += stride) {
    int e = i >> 4;
    int q = i & 15;
    int n = eidx[e];
    const float4 v = *reinterpret_cast<const float4*>(edge_attr + (size_t)e * DD + q * 4);
    float* dst = node_sum + (size_t)n * DD + q * 4;
    atomicAdd(dst + 0, v.x);
    atomicAdd(dst + 1, v.y);
    atomicAdd(dst + 2, v.z);
    atomicAdd(dst + 3, v.w);
  }
  for (int e = gid; e < E; e += stride) atomicAdd(&node_cnt[eidx[e]], 1.0f);
}

// ===========================================================================
// Pool: one block per graph; batch sorted -> binary search range.
// PREMEAN=true: nodeA already holds per-node means. Else divide by node_cnt.
// ===========================================================================
template <bool PREMEAN>
__global__ __launch_bounds__(256) void k_pool(const float* __restrict__ nodeA,
                                              const float* __restrict__ node_cnt,
                                              const float* __restrict__ x,
                                              const float* __restrict__ u,
                                              const int* __restrict__ batch,
                                              float* __restrict__ comb, int N) {
  __shared__ int s_lo, s_hi;
  __shared__ float rE[4][64], rV[4][64];
  int b = blockIdx.x;
  int tid = threadIdx.x;
  if (tid == 0) {
    int lo = 0, hi = N;
    while (lo < hi) { int m = (lo + hi) >> 1; if (batch[m] < b) lo = m + 1; else hi = m; }
    s_lo = lo;
    hi = N;
    while (lo < hi) { int m = (lo + hi) >> 1; if (batch[m] < b + 1) lo = m + 1; else hi = m; }
    s_hi = lo;
  }
  __syncthreads();
  int lo = s_lo, hi = s_hi;
  int d = tid & 63, sub = tid >> 6;
  float accE = 0.f, accV = 0.f;
  for (int n = lo + sub; n < hi; n += 4) {
    if (PREMEAN) {
      accE += nodeA[(size_t)n * DD + d];
    } else {
      float c = node_cnt[n];
      accE += nodeA[(size_t)n * DD + d] * (1.0f / fmaxf(c, 1.0f));
    }
    accV += x[(size_t)n * DD + d];
  }
  rE[sub][d] = accE;
  rV[sub][d] = accV;
  __syncthreads();
  if (sub == 0) {
    float cnt = fmaxf((float)(hi - lo), 1.0f);
    float ue = (rE[0][d] + rE[1][d] + rE[2][d] + rE[3][d]) / cnt;
    float uv = (rV[0][d] + rV[1][d] + rV[2][d] + rV[3][d]) / cnt;
    float* row = comb + (size_t)b * 192;
    row[d] = ue;
    row[64 + d] = uv;
    row[128 + d] = u[(size_t)b * 64 + d];
  }
}

// ===========================================================================
// Fused 3-layer MLP + BatchNorm, single 1024-thread block (unchanged, proven).
// ===========================================================================
template <int K, bool FIRST, bool LAST>
__device__ __forceinline__ void layer(int tid, const float* __restrict__ gin,
                                      float* wT, float* hbuf, float* ps, float* pq,
                                      float* abuf, float* bbuf,
                                      const float* __restrict__ W,
                                      const float* __restrict__ bias,
                                      const float* __restrict__ gamma,
                                      const float* __restrict__ beta,
                                      float* __restrict__ out) {
  int r = tid >> 2, cb = tid & 3, c0 = cb * 16;
  for (int i = tid; i < K * 64; i += 1024) {
    int k = i >> 6;
    int j = i & 63;
    wT[i] = W[j * K + k];
  }
  __syncthreads();

  float acc[16];
#pragma unroll
  for (int jj = 0; jj < 16; ++jj) acc[jj] = bias[c0 + jj];

  for (int k = 0; k < K; ++k) {
    float c = FIRST ? gin[(size_t)r * 192 + k] : hbuf[r * 65 + k];
    const float4* wp = reinterpret_cast<const float4*>(&wT[k * 64 + c0]);
#pragma unroll
    for (int jv = 0; jv < 4; ++jv) {
      float4 w = wp[jv];
      acc[jv * 4 + 0] += c * w.x;
      acc[jv * 4 + 1] += c * w.y;
      acc[jv * 4 + 2] += c * w.z;
      acc[jv * 4 + 3] += c * w.w;
    }
  }
#pragma unroll
  for (int jj = 0; jj < 16; ++jj) acc[jj] = fmaxf(acc[jj], 0.f);

  __syncthreads();
#pragma unroll
  for (int jj = 0; jj < 16; ++jj) hbuf[r * 65 + c0 + jj] = acc[jj];
  __syncthreads();

  {
    int col = tid & 63, seg = tid >> 6;
    float s = 0.f, sq = 0.f;
#pragma unroll
    for (int t = 0; t < 16; ++t) {
      float v = hbuf[(seg * 16 + t) * 65 + col];
      s += v;
      sq += v * v;
    }
    ps[seg * 64 + col] = s;
    pq[seg * 64 + col] = sq;
  }
  __syncthreads();
  if (tid < 64) {
    float s = 0.f, sq = 0.f;
#pragma unroll
    for (int g = 0; g < 16; ++g) {
      s += ps[g * 64 + tid];
      sq += pq[g * 64 + tid];
    }
    float mu = s * (1.0f / 256.0f);
    float var = sq * (1.0f / 256.0f) - mu * mu;
    float rs = rsqrtf(var + 1e-5f);
    float ga = gamma[tid] * rs;
    abuf[tid] = ga;
    bbuf[tid] = beta[tid] - mu * ga;
  }
  __syncthreads();
#pragma unroll
  for (int jj = 0; jj < 16; ++jj) {
    float v = acc[jj] * abuf[c0 + jj] + bbuf[c0 + jj];
    if (LAST)
      out[(size_t)r * 64 + c0 + jj] = v;
    else
      hbuf[r * 65 + c0 + jj] = v;
  }
  if (!LAST) __syncthreads();
}

__global__ __launch_bounds__(1024) void k_mlp(const float* __restrict__ comb,
                                              const float* W0, const float* b0,
                                              const float* W1, const float* b1,
                                              const float* W2, const float* b2,
                                              const float* g0, const float* be0,
                                              const float* g1, const float* be1,
                                              const float* g2, const float* be2,
                                              float* __restrict__ out) {
  __shared__ float wT[192 * 64];
  __shared__ float hbuf[256 * 65];
  __shared__ float ps[16 * 64], pq[16 * 64];
  __shared__ float abuf[64], bbuf[64];
  int tid = threadIdx.x;
  layer<192, true, false>(tid, comb, wT, hbuf, ps, pq, abuf, bbuf, W0, b0, g0, be0, nullptr);
  layer<64, false, false>(tid, comb, wT, hbuf, ps, pq, abuf, bbuf, W1, b1, g1, be1, nullptr);
  layer<64, false, true>(tid, comb, wT, hbuf, ps, pq, abuf, bbuf, W2, b2, g2, be2, out);
}

extern "C" void kernel_launch(void* const* d_in, const int* in_sizes, int n_in,
                              void* d_out, int out_size, void* d_ws, size_t ws_size,
                              hipStream_t stream) {
  (void)n_in; (void)out_size;
  const float* x         = (const float*)d_in[0];
  const float* edge_attr = (const float*)d_in[1];
  const float* u         = (const float*)d_in[2];
  const int*   eidx      = (const int*)d_in[3];  // row 0 = first E entries
  const int*   batch     = (const int*)d_in[4];
  const float* W0 = (const float*)d_in[5];
  const float* b0 = (const float*)d_in[6];
  const float* W1 = (const float*)d_in[7];
  const float* b1 = (const float*)d_in[8];
  const float* W2 = (const float*)d_in[9];
  const float* b2 = (const float*)d_in[10];
  const float* g0 = (const float*)d_in[11];
  const float* be0 = (const float*)d_in[12];
  const float* g1 = (const float*)d_in[13];
  const float* be1 = (const float*)d_in[14];
  const float* g2 = (const float*)d_in[15];
  const float* be2 = (const float*)d_in[16];

  int N = in_sizes[0] / DD;
  int E = in_sizes[1] / DD;
  int B = in_sizes[2] / DD;

  // CSR-path workspace layout
  size_t need = (size_t)N * DD * 4           // node_mean
              + (size_t)B * 192 * 4          // comb
              + (size_t)N * 4                // cnt
              + (size_t)(N + 1) * 4          // offs
              + (size_t)N * 4                // cursor
              + (size_t)E * 4 + 64;          // eids

  if (ws_size >= need) {
    float* node_mean = (float*)d_ws;
    float* comb = node_mean + (size_t)N * DD;
    int* cnt = (int*)(comb + (size_t)B * 192);
    int* offs = cnt + N;
    int* cursor = offs + N + 1;
    int* eids = cursor + N;

    hipMemsetAsync(cnt, 0, (size_t)N * sizeof(int), stream);
    k_hist<<<2048, 256, 0, stream>>>(eidx, cnt, E);
    k_scan<<<1, 1024, 0, stream>>>(cnt, offs, cursor, N);
    k_fill<<<2048, 256, 0, stream>>>(eidx, cursor, eids, E);
    k_gather<<<(N + 15) / 16, 256, 0, stream>>>(edge_attr, eids, offs, node_mean, N);
    k_pool<true><<<B, 256, 0, stream>>>(node_mean, nullptr, x, u, batch, comb, N);
    k_mlp<<<1, 1024, 0, stream>>>(comb, W0, b0, W1, b1, W2, b2,
                                  g0, be0, g1, be1, g2, be2, (float*)d_out);
  } else {
    // fallback: round-1 atomic path (fits in N*64 + N + B*192 floats)
    float* node_sum = (float*)d_ws;
    float* node_cnt = node_sum + (size_t)N * DD;
    float* comb = node_cnt + N;
    hipMemsetAsync(node_sum, 0, (size_t)(N * DD + N) * sizeof(float), stream);
    k_scatter<<<4096, 256, 0, stream>>>(edge_attr, eidx, node_sum, node_cnt, E);
    k_pool<false><<<B, 256, 0, stream>>>(node_sum, node_cnt, x, u, batch, comb, N);
    k_mlp<<<1, 1024, 0, stream>>>(comb, W0, b0, W1, b1, W2, b2,
                                  g0, be0, g1, be1, g2, be2, (float*)d_out);
  }
}